// Round 1
// baseline (758.389 us; speedup 1.0000x reference)
//
#include <hip/hip_runtime.h>
#include <math.h>

#define S_N   4
#define C_N   1024
#define N_N   131072
#define DK_N  128
#define DA_N  2048
#define MTOP  32
#define KMAX  64
#define B_N   64
#define NPC   128      // N/C
#define MCAND 4096     // MTOP*NPC
#define KTOT  512      // S*DK
#define EPSF  1e-8f

// ---------------- zero the atomic softmax sums ----------------
__global__ void k_init(float* sums) { sums[threadIdx.x] = 0.0f; }

// ---------------- queries: qw[b, s*128+k] = w_s * q_norm[b,s,k] ----------------
__global__ __launch_bounds__(256) void k_queries(const float* __restrict__ z,
                                                 const float* __restrict__ wqm,
                                                 const float* __restrict__ aw,
                                                 float* __restrict__ qw) {
    __shared__ __align__(16) float zl[DA_N];
    __shared__ float ql[DK_N];
    __shared__ float red[2];
    const int t = threadIdx.x;
    const int s = blockIdx.x >> 6;
    const int b = blockIdx.x & 63;
    const float4* zr = (const float4*)(z + (size_t)b * DA_N);
    float4* zl4 = (float4*)zl;
    for (int i = t; i < DA_N / 4; i += 256) zl4[i] = zr[i];
    __syncthreads();
    const int wave = t >> 6, lane = t & 63;
    for (int kw = 0; kw < 32; ++kw) {
        int k = wave * 32 + kw;
        const float* wr = wqm + ((size_t)(s * DK_N + k)) * DA_N;
        float acc = 0.f;
        #pragma unroll
        for (int i = 0; i < 32; ++i) acc += wr[i * 64 + lane] * zl[i * 64 + lane];
        for (int m = 32; m >= 1; m >>= 1) acc += __shfl_xor(acc, m, 64);
        if (lane == 0) ql[k] = acc;
    }
    __syncthreads();
    if (t < 128) {
        float v = ql[t];
        float p = v * v;
        for (int m = 32; m >= 1; m >>= 1) p += __shfl_xor(p, m, 64);
        if ((t & 63) == 0) red[t >> 6] = p;
    }
    __syncthreads();
    if (t < 128) {
        float ss = red[0] + red[1];
        float inv = 1.0f / (sqrtf(ss) + EPSF);
        float a0 = aw[0], a1 = aw[1], a2 = aw[2], a3 = aw[3];
        float mx = fmaxf(fmaxf(a0, a1), fmaxf(a2, a3));
        float e0 = expf(a0 - mx), e1 = expf(a1 - mx), e2 = expf(a2 - mx), e3 = expf(a3 - mx);
        float wsum = e0 + e1 + e2 + e3;
        float wv = (s == 0 ? e0 : s == 1 ? e1 : s == 2 ? e2 : e3) / wsum;
        qw[(size_t)b * KTOT + s * DK_N + t] = wv * inv * ql[t];
    }
}

// ---------------- normalize centroids ----------------
__global__ __launch_bounds__(256) void k_cnorm(const float* __restrict__ cent,
                                               float* __restrict__ cn) {
    const int t = threadIdx.x;
    const int wave = t >> 6, lane = t & 63;
    const int row = blockIdx.x * 4 + wave;  // < 4096
    const float2* cr = (const float2*)(cent + (size_t)row * DK_N);
    float2 v = cr[lane];
    float p = v.x * v.x + v.y * v.y;
    for (int m = 32; m >= 1; m >>= 1) p += __shfl_xor(p, m, 64);
    float inv = 1.0f / (sqrtf(p) + EPSF);
    float2* o = (float2*)(cn + (size_t)row * DK_N);
    o[lane] = make_float2(v.x * inv, v.y * inv);
}

// ---------------- centroid scores (f64 accumulate for stable ordering) ----------------
__global__ __launch_bounds__(256) void k_cscore(const float* __restrict__ qw,
                                                const float* __restrict__ cn,
                                                double* __restrict__ cs) {
    __shared__ __align__(16) float qwl[KTOT];
    const int t = threadIdx.x;
    const int b = blockIdx.x >> 2;
    const int cq = blockIdx.x & 3;
    qwl[t] = qw[(size_t)b * KTOT + t];
    qwl[t + 256] = qw[(size_t)b * KTOT + t + 256];
    __syncthreads();
    const int c = cq * 256 + t;
    double acc = 0.0;
    #pragma unroll
    for (int s = 0; s < 4; ++s) {
        const float* qs = qwl + s * DK_N;
        const float4* cp = (const float4*)(cn + ((size_t)(s * C_N + c)) * DK_N);
        #pragma unroll 8
        for (int k4 = 0; k4 < 32; ++k4) {
            float4 f = cp[k4];
            acc += (double)qs[k4 * 4 + 0] * f.x + (double)qs[k4 * 4 + 1] * f.y
                 + (double)qs[k4 * 4 + 2] * f.z + (double)qs[k4 * 4 + 3] * f.w;
        }
    }
    cs[(size_t)b * C_N + c] = acc;
}

// ---------------- top-32 clusters per b + inverse map ----------------
__global__ __launch_bounds__(256) void k_top32(const double* __restrict__ cs,
                                               int* __restrict__ topc,
                                               int* __restrict__ invm) {
    __shared__ double val[C_N];
    __shared__ double wvs[4];
    __shared__ int wis[4];
    const int t = threadIdx.x;
    const int b = blockIdx.x;
    #pragma unroll
    for (int r = 0; r < 4; ++r) {
        val[r * 256 + t] = cs[(size_t)b * C_N + r * 256 + t];
        invm[b * C_N + r * 256 + t] = -1;
    }
    __syncthreads();
    for (int it = 0; it < MTOP; ++it) {
        double bv = -1e300; int bi = -1;
        #pragma unroll
        for (int r = 0; r < 4; ++r) {
            int cc = r * 256 + t;
            double v = val[cc];
            if (v > bv || (v == bv && (unsigned)cc < (unsigned)bi)) { bv = v; bi = cc; }
        }
        for (int m = 32; m >= 1; m >>= 1) {
            double ov = __shfl_xor(bv, m, 64);
            int oi = __shfl_xor(bi, m, 64);
            if (ov > bv || (ov == bv && (unsigned)oi < (unsigned)bi)) { bv = ov; bi = oi; }
        }
        if ((t & 63) == 0) { wvs[t >> 6] = bv; wis[t >> 6] = bi; }
        __syncthreads();
        if (t == 0) {
            double cbv = wvs[0]; int cbi = wis[0];
            for (int w = 1; w < 4; ++w)
                if (wvs[w] > cbv || (wvs[w] == cbv && (unsigned)wis[w] < (unsigned)cbi)) { cbv = wvs[w]; cbi = wis[w]; }
            topc[b * MTOP + it] = cbi;
            invm[b * C_N + cbi] = it;
            val[cbi] = -1e300;
        }
        __syncthreads();
    }
}

// ---------------- dense pass: exp(s_full) + atomic sums + fused f64 refine ----------------
__global__ __launch_bounds__(256, 4) void k_dense(const float* __restrict__ keys,
                                                  const float* __restrict__ qw,
                                                  const int* __restrict__ invm,
                                                  double* __restrict__ si,
                                                  float* __restrict__ out_soft,
                                                  float* __restrict__ sums) {
    __shared__ __align__(16) float keyl[32 * 196];   // [k][noff(n)] swizzled
    __shared__ __align__(16) float qwl[32 * 68];     // [k][b] padded
    __shared__ float invn[128];
    __shared__ int hb[64], hj[64];
    __shared__ int hcnt;
    const int t = threadIdx.x;
    const int cl = blockIdx.x;       // tile == one IVF cluster
    const int n0 = cl * NPC;
    if (t == 0) hcnt = 0;
    __syncthreads();
    if (t < 64) {
        int j = invm[t * C_N + cl];
        if (j >= 0) { int p = atomicAdd(&hcnt, 1); hb[p] = t; hj[p] = j; }
    }
    const int nq = t & 15, bq = t >> 4;
    float acc[4][8];
    #pragma unroll
    for (int i = 0; i < 4; ++i)
        #pragma unroll
        for (int j = 0; j < 8; ++j) acc[i][j] = 0.f;

    for (int c = 0; c < 16; ++c) {
        const int s = c >> 2;
        const int koff = (c & 3) * 32;
        if ((c & 3) == 0) {
            __syncthreads();
            // per-s row norms (this read is the HBM first-touch; restage hits L1/L2)
            int row = t >> 1, half = t & 1;
            const float4* kp4 = (const float4*)(keys + ((size_t)(s * N_N + n0 + row)) * DK_N + half * 64);
            float ssq = 0.f;
            #pragma unroll
            for (int i = 0; i < 16; ++i) {
                float4 f = kp4[i];
                ssq += f.x * f.x + f.y * f.y + f.z * f.z + f.w * f.w;
            }
            ssq += __shfl_xor(ssq, 1, 64);
            if (half == 0) invn[row] = 1.0f / (sqrtf(ssq) + EPSF);
            __syncthreads();
        }
        // stage keys: 128 n x 32 k, scaled by inv-norm, rotated writes to dodge conflicts
        #pragma unroll
        for (int rep = 0; rep < 4; ++rep) {
            int idx = rep * 256 + t;
            int kk4 = idx & 7;
            int n = idx >> 3;
            const float4 v = *(const float4*)(keys + ((size_t)(s * N_N + n0 + n)) * DK_N + koff + kk4 * 4);
            float sc = invn[n];
            int noffn = n + ((n >> 3) << 2);
            float vv[4] = {v.x * sc, v.y * sc, v.z * sc, v.w * sc};
            #pragma unroll
            for (int jj = 0; jj < 4; ++jj) {
                int j2 = (kk4 + jj) & 3;
                keyl[(kk4 * 4 + j2) * 196 + noffn] = vv[j2];
            }
        }
        // stage qw: 64 b x 32 k
        #pragma unroll
        for (int rep = 0; rep < 2; ++rep) {
            int idx = rep * 256 + t;
            int kk4 = idx & 7;
            int b = idx >> 3;
            const float4 v = *(const float4*)(qw + (size_t)b * KTOT + c * 32 + kk4 * 4);
            float vv[4] = {v.x, v.y, v.z, v.w};
            #pragma unroll
            for (int jj = 0; jj < 4; ++jj) {
                int j2 = (kk4 + jj) & 3;
                qwl[(kk4 * 4 + j2) * 68 + b] = vv[j2];
            }
        }
        __syncthreads();
        // register-tiled f32 GEMM chunk
        #pragma unroll 4
        for (int k = 0; k < 32; ++k) {
            const float4 qv = *(const float4*)&qwl[k * 68 + bq * 4];
            const float4 ka = *(const float4*)&keyl[k * 196 + nq * 12];
            const float4 kb = *(const float4*)&keyl[k * 196 + nq * 12 + 4];
            const float qr[4] = {qv.x, qv.y, qv.z, qv.w};
            const float kr[8] = {ka.x, ka.y, ka.z, ka.w, kb.x, kb.y, kb.z, kb.w};
            #pragma unroll
            for (int i = 0; i < 4; ++i)
                #pragma unroll
                for (int j = 0; j < 8; ++j)
                    acc[i][j] += qr[i] * kr[j];
        }
        // fused f64 refine for candidate (b, cluster) pairs — same thread owns same
        // (b,j,n) every chunk, so plain global RMW accumulation is race-free.
        const int nh = hcnt;
        for (int h = 0; h < nh; ++h) {
            const int b = hb[h], j = hj[h];
            const int n = t >> 1, half = t & 1;
            const int noffn = n + ((n >> 3) << 2);
            double a = 0.0;
            #pragma unroll
            for (int kk2 = 0; kk2 < 16; ++kk2) {
                int kk = half * 16 + kk2;
                a += (double)qwl[kk * 68 + b] * (double)keyl[kk * 196 + noffn];
            }
            a += __shfl_xor(a, 1, 64);
            if (half == 0) {
                double* sp = si + (size_t)b * MCAND + j * NPC + n;
                if (c == 0) *sp = a;
                else *sp += a;
            }
        }
        __syncthreads();
    }
    // epilogue: scores in [-1,1] -> exp without max-subtraction is exact-stable
    #pragma unroll
    for (int i = 0; i < 4; ++i) {
        int b = bq * 4 + i;
        float e[8]; float se = 0.f;
        #pragma unroll
        for (int j = 0; j < 8; ++j) { e[j] = expf(acc[i][j]); se += e[j]; }
        float4* op = (float4*)(out_soft + (size_t)b * N_N + n0 + nq * 8);
        op[0] = make_float4(e[0], e[1], e[2], e[3]);
        op[1] = make_float4(e[4], e[5], e[6], e[7]);
        #pragma unroll
        for (int m = 8; m >= 1; m >>= 1) se += __shfl_xor(se, m, 16);
        if ((t & 15) == 0) atomicAdd(&sums[b], se);
    }
}

// ---------------- per-b top-64 over 4096 candidates + alphas + idx ----------------
__global__ __launch_bounds__(256) void k_top64(const double* __restrict__ si,
                                               const int* __restrict__ topc,
                                               const float* __restrict__ taup,
                                               const float* __restrict__ lamp,
                                               const int* __restrict__ warmp,
                                               float* __restrict__ out_alpha,
                                               float* __restrict__ out_idx) {
    __shared__ double key64[MCAND];
    __shared__ float aux[MCAND];
    __shared__ double rs[4];
    __shared__ double wvs[4];
    __shared__ int wis[4];
    __shared__ int sel[KMAX];
    const int t = threadIdx.x;
    const int b = blockIdx.x;
    const int warm = *warmp;
    const float lamf = *lamp, tauf = *taup;
    double loc = 0.0;
    for (int r = 0; r < 16; ++r) {
        int j = r * 256 + t;
        double sd = si[(size_t)b * MCAND + j];
        float sf = (float)sd;
        if (warm) {
            key64[j] = sd;
            aux[j] = sf;
        } else {
            float g = 1.0f / (1.0f + expf(-lamf * (sf - tauf)));
            float raw = g * expf(sf);                 // T = 1
            aux[j] = raw;
            loc += (double)raw;
            double x = (double)lamf * (sd - (double)tauf);
            key64[j] = sd - log1p(exp(-x));           // log(raw): monotone-safe key
        }
    }
    for (int m = 32; m >= 1; m >>= 1) loc += __shfl_xor(loc, m, 64);
    if ((t & 63) == 0) rs[t >> 6] = loc;
    __syncthreads();
    const float S_all = (float)(rs[0] + rs[1] + rs[2] + rs[3]);
    for (int it = 0; it < KMAX; ++it) {
        double bv = -1e300; int bi = -1;
        for (int r = 0; r < 16; ++r) {
            int j = r * 256 + t;
            double v = key64[j];
            if (v > bv || (v == bv && (unsigned)j < (unsigned)bi)) { bv = v; bi = j; }
        }
        for (int m = 32; m >= 1; m >>= 1) {
            double ov = __shfl_xor(bv, m, 64);
            int oi = __shfl_xor(bi, m, 64);
            if (ov > bv || (ov == bv && (unsigned)oi < (unsigned)bi)) { bv = ov; bi = oi; }
        }
        if ((t & 63) == 0) { wvs[t >> 6] = bv; wis[t >> 6] = bi; }
        __syncthreads();
        if (t == 0) {
            double cbv = wvs[0]; int cbi = wis[0];
            for (int w = 1; w < 4; ++w)
                if (wvs[w] > cbv || (wvs[w] == cbv && (unsigned)wis[w] < (unsigned)cbi)) { cbv = wvs[w]; cbi = wis[w]; }
            sel[it] = cbi;
            key64[cbi] = -1e300;
        }
        __syncthreads();
    }
    if (t < KMAX) {
        int j = sel[t];
        float numer;
        if (warm) numer = expf(aux[j]);
        else numer = aux[j] / (S_all + EPSF);
        float tot = numer;
        for (int m = 32; m >= 1; m >>= 1) tot += __shfl_xor(tot, m, 64);
        float denom = warm ? tot : (tot + EPSF);
        float alpha = numer / denom;
        out_alpha[b * KMAX + t] = alpha;
        int cl2 = topc[b * MTOP + (j >> 7)];
        out_idx[b * KMAX + t] = (float)(cl2 * NPC + (j & 127));
    }
}

// ---------------- soft_full normalize ----------------
__global__ void k_norm(float* __restrict__ out_soft, const float* __restrict__ sums) {
    const int b = blockIdx.x >> 7;
    const int p = (blockIdx.x & 127) * 256 + threadIdx.x;
    const float inv = 1.0f / sums[b];
    float4* p4 = (float4*)(out_soft + (size_t)b * N_N) + p;
    float4 v = *p4;
    v.x *= inv; v.y *= inv; v.z *= inv; v.w *= inv;
    *p4 = v;
}

extern "C" void kernel_launch(void* const* d_in, const int* in_sizes, int n_in,
                              void* d_out, int out_size, void* d_ws, size_t ws_size,
                              hipStream_t stream) {
    const float* z    = (const float*)d_in[0];
    const float* keys = (const float*)d_in[1];
    const float* wqm  = (const float*)d_in[2];
    const float* aw   = (const float*)d_in[3];
    const float* tau  = (const float*)d_in[4];
    const float* cent = (const float*)d_in[5];
    const float* lam  = (const float*)d_in[6];
    const int*   warm = (const int*)d_in[7];
    float* out = (float*)d_out;
    float* out_alpha = out;                    // [64,64]
    float* out_idx   = out + B_N * KMAX;       // [64,64] (written as float values)
    float* out_soft  = out + 2 * B_N * KMAX;   // [64,131072]
    char* ws = (char*)d_ws;
    float*  qw   = (float*)(ws + 0);           // 131072 B
    float*  cn   = (float*)(ws + 131072);      // 2 MB
    double* cs   = (double*)(ws + 2228224);    // 512 KB
    int*    topc = (int*)(ws + 2752512);       // 8 KB
    int*    invm = (int*)(ws + 2760704);       // 256 KB
    double* si   = (double*)(ws + 3022848);    // 2 MB
    float*  sums = (float*)(ws + 5120000);     // 256 B

    hipLaunchKernelGGL(k_init,    dim3(1),    dim3(64),  0, stream, sums);
    hipLaunchKernelGGL(k_queries, dim3(256),  dim3(256), 0, stream, z, wqm, aw, qw);
    hipLaunchKernelGGL(k_cnorm,   dim3(1024), dim3(256), 0, stream, cent, cn);
    hipLaunchKernelGGL(k_cscore,  dim3(256),  dim3(256), 0, stream, qw, cn, cs);
    hipLaunchKernelGGL(k_top32,   dim3(64),   dim3(256), 0, stream, cs, topc, invm);
    hipLaunchKernelGGL(k_dense,   dim3(1024), dim3(256), 0, stream, keys, qw, invm, si, out_soft, sums);
    hipLaunchKernelGGL(k_top64,   dim3(64),   dim3(256), 0, stream, si, topc, tau, lam, warm, out_alpha, out_idx);
    hipLaunchKernelGGL(k_norm,    dim3(8192), dim3(256), 0, stream, out_soft, sums);
}

// Round 3
// 687.981 us; speedup vs baseline: 1.1023x; 1.1023x over previous
//
#include <hip/hip_runtime.h>
#include <math.h>

#define S_N   4
#define C_N   1024
#define N_N   131072
#define DK_N  128
#define DA_N  2048
#define MTOP  32
#define KMAX  64
#define B_N   64
#define NPC   128      // N/C
#define MCAND 4096     // MTOP*NPC
#define KTOT  512      // S*DK
#define EPSF  1e-8f
#define KPAD  40       // bf16 elems per LDS row (32 + 8 pad), row = 80 B

typedef short s8v __attribute__((ext_vector_type(8)));
typedef float f4v __attribute__((ext_vector_type(4)));

__device__ __forceinline__ unsigned short f2bf(float x) {
    unsigned u = __float_as_uint(x);
    return (unsigned short)((u + 0x7FFFu + ((u >> 16) & 1u)) >> 16);
}

// ---------------- zero the atomic softmax sums ----------------
__global__ void k_init(float* sums) { sums[threadIdx.x] = 0.0f; }

// ---------------- queries: qw[b, s*128+k] = w_s * q_norm[b,s,k] ----------------
__global__ __launch_bounds__(256) void k_queries(const float* __restrict__ z,
                                                 const float* __restrict__ wqm,
                                                 const float* __restrict__ aw,
                                                 float* __restrict__ qw) {
    __shared__ __align__(16) float zl[DA_N];
    __shared__ float ql[DK_N];
    __shared__ float red[2];
    const int t = threadIdx.x;
    const int s = blockIdx.x >> 6;
    const int b = blockIdx.x & 63;
    const float4* zr = (const float4*)(z + (size_t)b * DA_N);
    float4* zl4 = (float4*)zl;
    for (int i = t; i < DA_N / 4; i += 256) zl4[i] = zr[i];
    __syncthreads();
    const int wave = t >> 6, lane = t & 63;
    for (int kw = 0; kw < 32; ++kw) {
        int k = wave * 32 + kw;
        const float* wr = wqm + ((size_t)(s * DK_N + k)) * DA_N;
        float acc = 0.f;
        #pragma unroll
        for (int i = 0; i < 32; ++i) acc += wr[i * 64 + lane] * zl[i * 64 + lane];
        for (int m = 32; m >= 1; m >>= 1) acc += __shfl_xor(acc, m, 64);
        if (lane == 0) ql[k] = acc;
    }
    __syncthreads();
    if (t < 128) {
        float v = ql[t];
        float p = v * v;
        for (int m = 32; m >= 1; m >>= 1) p += __shfl_xor(p, m, 64);
        if ((t & 63) == 0) red[t >> 6] = p;
    }
    __syncthreads();
    if (t < 128) {
        float ss = red[0] + red[1];
        float inv = 1.0f / (sqrtf(ss) + EPSF);
        float a0 = aw[0], a1 = aw[1], a2 = aw[2], a3 = aw[3];
        float mx = fmaxf(fmaxf(a0, a1), fmaxf(a2, a3));
        float e0 = expf(a0 - mx), e1 = expf(a1 - mx), e2 = expf(a2 - mx), e3 = expf(a3 - mx);
        float wsum = e0 + e1 + e2 + e3;
        float wv = (s == 0 ? e0 : s == 1 ? e1 : s == 2 ? e2 : e3) / wsum;
        qw[(size_t)b * KTOT + s * DK_N + t] = wv * inv * ql[t];
    }
}

// ---------------- normalize centroids ----------------
__global__ __launch_bounds__(256) void k_cnorm(const float* __restrict__ cent,
                                               float* __restrict__ cn) {
    const int t = threadIdx.x;
    const int wave = t >> 6, lane = t & 63;
    const int row = blockIdx.x * 4 + wave;  // < 4096
    const float2* cr = (const float2*)(cent + (size_t)row * DK_N);
    float2 v = cr[lane];
    float p = v.x * v.x + v.y * v.y;
    for (int m = 32; m >= 1; m >>= 1) p += __shfl_xor(p, m, 64);
    float inv = 1.0f / (sqrtf(p) + EPSF);
    float2* o = (float2*)(cn + (size_t)row * DK_N);
    o[lane] = make_float2(v.x * inv, v.y * inv);
}

// ---------------- centroid scores (f64 accumulate for stable ordering) ----------------
// grid 1024: b = blk>>4, cq = blk&15 (64 c each); thread = (s, c_local)
__global__ __launch_bounds__(256) void k_cscore(const float* __restrict__ qw,
                                                const float* __restrict__ cn,
                                                double* __restrict__ cs) {
    __shared__ __align__(16) float qwl[KTOT];
    __shared__ double part[4][64];
    const int t = threadIdx.x;
    const int b = blockIdx.x >> 4;
    const int cq = blockIdx.x & 15;
    qwl[t] = qw[(size_t)b * KTOT + t];
    qwl[t + 256] = qw[(size_t)b * KTOT + t + 256];
    __syncthreads();
    const int cl = t & 63, s = t >> 6;
    const int c = cq * 64 + cl;
    const float* qs = qwl + s * DK_N;
    const float4* cp = (const float4*)(cn + ((size_t)(s * C_N + c)) * DK_N);
    double acc = 0.0;
    #pragma unroll 8
    for (int k4 = 0; k4 < 32; ++k4) {
        float4 f = cp[k4];
        acc += (double)qs[k4 * 4 + 0] * f.x + (double)qs[k4 * 4 + 1] * f.y
             + (double)qs[k4 * 4 + 2] * f.z + (double)qs[k4 * 4 + 3] * f.w;
    }
    part[s][cl] = acc;
    __syncthreads();
    if (t < 64) cs[(size_t)b * C_N + cq * 64 + t] = part[0][t] + part[1][t] + part[2][t] + part[3][t];
}

// ---------------- top-32 clusters per b + inverse map ----------------
__global__ __launch_bounds__(256) void k_top32(const double* __restrict__ cs,
                                               int* __restrict__ topc,
                                               int* __restrict__ invm) {
    __shared__ double val[C_N];
    __shared__ double wvs[4];
    __shared__ int wis[4];
    const int t = threadIdx.x;
    const int b = blockIdx.x;
    #pragma unroll
    for (int r = 0; r < 4; ++r) {
        val[r * 256 + t] = cs[(size_t)b * C_N + r * 256 + t];
        invm[b * C_N + r * 256 + t] = -1;
    }
    __syncthreads();
    for (int it = 0; it < MTOP; ++it) {
        double bv = -1e300; int bi = -1;
        #pragma unroll
        for (int r = 0; r < 4; ++r) {
            int cc = r * 256 + t;
            double v = val[cc];
            if (v > bv || (v == bv && (unsigned)cc < (unsigned)bi)) { bv = v; bi = cc; }
        }
        for (int m = 32; m >= 1; m >>= 1) {
            double ov = __shfl_xor(bv, m, 64);
            int oi = __shfl_xor(bi, m, 64);
            if (ov > bv || (ov == bv && (unsigned)oi < (unsigned)bi)) { bv = ov; bi = oi; }
        }
        if ((t & 63) == 0) { wvs[t >> 6] = bv; wis[t >> 6] = bi; }
        __syncthreads();
        if (t == 0) {
            double cbv = wvs[0]; int cbi = wis[0];
            for (int w = 1; w < 4; ++w)
                if (wvs[w] > cbv || (wvs[w] == cbv && (unsigned)wis[w] < (unsigned)cbi)) { cbv = wvs[w]; cbi = wis[w]; }
            topc[b * MTOP + it] = cbi;
            invm[b * C_N + cbi] = it;
            val[cbi] = -1e300;
        }
        __syncthreads();
    }
}

// ---------------- dense pass: bf16 MFMA for exp(s_full) + fused f64 refine ----------------
// tile: 128 n (one cluster) x 64 b, K staged 32 at a time
__global__ __launch_bounds__(256, 4) void k_dense(const float* __restrict__ keys,
                                                  const float* __restrict__ qw,
                                                  const int* __restrict__ invm,
                                                  double* __restrict__ si,
                                                  float* __restrict__ out_soft,
                                                  float* __restrict__ sums) {
    __shared__ __align__(16) unsigned short keyl[128 * KPAD]; // bf16 [n][k], row 80 B
    __shared__ __align__(16) unsigned short qbl[64 * KPAD];   // bf16 [b][k]
    __shared__ float qf32l[32 * 68];                          // f32 [k][b] for refine
    __shared__ float invn[128];
    __shared__ double hacc[8 * 128];                          // f64 refine accumulators
    __shared__ int hb[64], hj[64];
    __shared__ int hcnt;
    const int t = threadIdx.x;
    const int cl = blockIdx.x;       // tile == one IVF cluster
    const int n0 = cl * NPC;
    const int lane = t & 63, w = t >> 6;
    const int quad = lane >> 4, col = lane & 15;
    if (t == 0) hcnt = 0;
    for (int i = t; i < 1024; i += 256) hacc[i] = 0.0;
    __syncthreads();
    if (t < 64) {
        int j = invm[t * C_N + cl];
        if (j >= 0) { int p = atomicAdd(&hcnt, 1); hb[p] = t; hj[p] = j; }
    }

    f4v acc[8];
    #pragma unroll
    for (int T = 0; T < 8; ++T) acc[T] = (f4v){0.f, 0.f, 0.f, 0.f};

    for (int c = 0; c < 16; ++c) {
        const int s = c >> 2;
        const int koff = (c & 3) * 32;
        if ((c & 3) == 0) {
            __syncthreads();   // also publishes hb/hj/hcnt at c==0
            int row = t >> 1, half = t & 1;
            const float4* kp4 = (const float4*)(keys + ((size_t)(s * N_N + n0 + row)) * DK_N + half * 64);
            float ssq = 0.f;
            #pragma unroll
            for (int i = 0; i < 16; ++i) {
                float4 f = kp4[i];
                ssq += f.x * f.x + f.y * f.y + f.z * f.z + f.w * f.w;
            }
            ssq += __shfl_xor(ssq, 1, 64);
            if (half == 0) invn[row] = 1.0f / (sqrtf(ssq) + EPSF);
            __syncthreads();
        }
        // stage keys: 128 n x 32 k f32 -> scaled bf16
        #pragma unroll
        for (int rep = 0; rep < 4; ++rep) {
            int idx = rep * 256 + t;
            int kk4 = idx & 7;
            int n = idx >> 3;
            const float4 v = *(const float4*)(keys + ((size_t)(s * N_N + n0 + n)) * DK_N + koff + kk4 * 4);
            float sc = invn[n];
            unsigned w0 = (unsigned)f2bf(v.x * sc) | ((unsigned)f2bf(v.y * sc) << 16);
            unsigned w1 = (unsigned)f2bf(v.z * sc) | ((unsigned)f2bf(v.w * sc) << 16);
            *(uint2*)&keyl[n * KPAD + kk4 * 4] = make_uint2(w0, w1);
        }
        // stage qw: 64 b x 32 k as bf16 + f32 copy for refine
        #pragma unroll
        for (int rep = 0; rep < 2; ++rep) {
            int idx = rep * 256 + t;
            int kk4 = idx & 7;
            int b = idx >> 3;
            const float4 v = *(const float4*)(qw + (size_t)b * KTOT + c * 32 + kk4 * 4);
            unsigned w0 = (unsigned)f2bf(v.x) | ((unsigned)f2bf(v.y) << 16);
            unsigned w1 = (unsigned)f2bf(v.z) | ((unsigned)f2bf(v.w) << 16);
            *(uint2*)&qbl[b * KPAD + kk4 * 4] = make_uint2(w0, w1);
            qf32l[(kk4 * 4 + 0) * 68 + b] = v.x;
            qf32l[(kk4 * 4 + 1) * 68 + b] = v.y;
            qf32l[(kk4 * 4 + 2) * 68 + b] = v.z;
            qf32l[(kk4 * 4 + 3) * 68 + b] = v.w;
        }
        __syncthreads();
        // MFMA: wave w computes b-rows [w*16, w*16+16), all 128 n
        const s8v a_frag = *(const s8v*)&qbl[(w * 16 + col) * KPAD + quad * 8];
        #pragma unroll
        for (int T = 0; T < 8; ++T) {
            const s8v b_frag = *(const s8v*)&keyl[(T * 16 + col) * KPAD + quad * 8];
            acc[T] = __builtin_amdgcn_mfma_f32_16x16x32_bf16(a_frag, b_frag, acc[T], 0, 0, 0);
        }
        // fused f64 refine: exact f32 keys re-read from global (L1-hot), q from f32 LDS.
        // FIX(r3): chunk contribution must be scaled by the key inverse-norm invn[n]
        // (round 2 dotted RAW keys -> si = ||k||*cos, wrong ordering -> idx absmax 1.3e5).
        const int nh = hcnt;
        for (int h = 0; h < nh; ++h) {
            const int b = hb[h], j = hj[h];
            const int n = t >> 1, half = t & 1;
            const float4* kp = (const float4*)(keys + ((size_t)(s * N_N + n0 + n)) * DK_N + koff + half * 16);
            double a = 0.0;
            #pragma unroll
            for (int e = 0; e < 4; ++e) {
                float4 kv = kp[e];
                int kb = half * 16 + e * 4;
                a += (double)qf32l[(kb + 0) * 68 + b] * kv.x
                   + (double)qf32l[(kb + 1) * 68 + b] * kv.y
                   + (double)qf32l[(kb + 2) * 68 + b] * kv.z
                   + (double)qf32l[(kb + 3) * 68 + b] * kv.w;
            }
            a += __shfl_xor(a, 1, 64);
            if (half == 0) {
                a *= (double)invn[n];   // normalize key for this aspect
                if (h < 8) hacc[h * 128 + n] += a;
                else {
                    double* sp = si + (size_t)b * MCAND + j * NPC + n;
                    if (c == 0) *sp = a;
                    else *sp += a;
                }
            }
        }
        __syncthreads();
    }
    // write refine results
    {
        const int nh = hcnt < 8 ? hcnt : 8;
        if (t < 128)
            for (int h = 0; h < nh; ++h)
                si[(size_t)hb[h] * MCAND + hj[h] * NPC + t] = hacc[h * 128 + t];
    }
    // epilogue: exp + per-b sums. D layout: b = w*16 + quad*4 + r, n = n0 + T*16 + col
    #pragma unroll
    for (int r = 0; r < 4; ++r) {
        const int b = w * 16 + quad * 4 + r;
        float se = 0.f;
        #pragma unroll
        for (int T = 0; T < 8; ++T) {
            float ev = expf(acc[T][r]);
            out_soft[(size_t)b * N_N + n0 + T * 16 + col] = ev;
            se += ev;
        }
        #pragma unroll
        for (int m = 8; m >= 1; m >>= 1) se += __shfl_xor(se, m, 64);
        if (col == 0) atomicAdd(&sums[b], se);
    }
}

// ---------------- per-b top-64: per-wave selection + wave-0 merge ----------------
__global__ __launch_bounds__(256) void k_top64(const double* __restrict__ si,
                                               const int* __restrict__ topc,
                                               const float* __restrict__ taup,
                                               const float* __restrict__ lamp,
                                               const int* __restrict__ warmp,
                                               float* __restrict__ out_alpha,
                                               float* __restrict__ out_idx) {
    __shared__ float aux[MCAND];
    __shared__ double selk[256];
    __shared__ int selj[256];
    __shared__ double rs[4];
    __shared__ int sel[KMAX];
    const int t = threadIdx.x;
    const int b = blockIdx.x;
    const int w = t >> 6, lane = t & 63;
    const int warm = *warmp;
    const float lamf = *lamp, tauf = *taup;
    double v[16];
    double loc = 0.0;
    #pragma unroll
    for (int r = 0; r < 16; ++r) {
        int j = w * 1024 + r * 64 + lane;
        double sd = si[(size_t)b * MCAND + j];
        float sf = (float)sd;
        double key;
        if (warm) {
            aux[j] = sf;
            key = sd;
        } else {
            float g = 1.0f / (1.0f + expf(-lamf * (sf - tauf)));
            float raw = g * expf(sf);               // T = 1
            aux[j] = raw;
            loc += (double)raw;
            // raw is monotone in s for lam>=0; only lam<0 needs the transform
            if (lamf >= 0.0f) key = sd;
            else {
                double x = (double)lamf * (sd - (double)tauf);
                key = sd - log1p(exp(-x));
            }
        }
        v[r] = key;
    }
    for (int m = 32; m >= 1; m >>= 1) loc += __shfl_xor(loc, m, 64);
    if (lane == 0) rs[w] = loc;
    // per-lane running best (tie -> smaller r == smaller j)
    double bv = -1e300; int br = -1;
    #pragma unroll
    for (int r = 0; r < 16; ++r)
        if (v[r] > bv) { bv = v[r]; br = r; }
    // per-wave top-64, sync-free
    for (int round = 0; round < KMAX; ++round) {
        double cv = bv;
        int cj = (br >= 0) ? (w * 1024 + br * 64 + lane) : 0x7FFFFFFF;
        #pragma unroll
        for (int m = 32; m >= 1; m >>= 1) {
            double ov = __shfl_xor(cv, m, 64);
            int oj = __shfl_xor(cj, m, 64);
            if (ov > cv || (ov == cv && oj < cj)) { cv = ov; cj = oj; }
        }
        if (lane == 0) { selk[w * 64 + round] = cv; selj[w * 64 + round] = cj; }
        if (cj == w * 1024 + br * 64 + lane) {
            v[br] = -1e300;
            bv = -1e300; br = -1;
            #pragma unroll
            for (int r = 0; r < 16; ++r)
                if (v[r] > bv) { bv = v[r]; br = r; }
        }
    }
    __syncthreads();
    // wave-0 merge of the 256 candidates
    if (w == 0) {
        double fv[4]; int fj[4];
        #pragma unroll
        for (int i = 0; i < 4; ++i) { fv[i] = selk[lane * 4 + i]; fj[i] = selj[lane * 4 + i]; }
        for (int round = 0; round < KMAX; ++round) {
            double cv = -1e300; int cj = 0x7FFFFFFF; int ci = -1;
            #pragma unroll
            for (int i = 0; i < 4; ++i)
                if (fv[i] > cv || (fv[i] == cv && fj[i] < cj)) { cv = fv[i]; cj = fj[i]; ci = i; }
            double wv2 = cv; int wj = cj;
            #pragma unroll
            for (int m = 32; m >= 1; m >>= 1) {
                double ov = __shfl_xor(wv2, m, 64);
                int oj = __shfl_xor(wj, m, 64);
                if (ov > wv2 || (ov == wv2 && oj < wj)) { wv2 = ov; wj = oj; }
            }
            if (wj == cj && ci >= 0) fv[ci] = -1e300;   // owner removes (unique j)
            if (lane == 0) sel[round] = wj;
        }
    }
    __syncthreads();
    const float S_all = (float)(rs[0] + rs[1] + rs[2] + rs[3]);
    if (t < KMAX) {
        int j = sel[t];
        float numer;
        if (warm) numer = expf(aux[j]);
        else numer = aux[j] / (S_all + EPSF);
        float tot = numer;
        for (int m = 32; m >= 1; m >>= 1) tot += __shfl_xor(tot, m, 64);
        float denom = warm ? tot : (tot + EPSF);
        float alpha = numer / denom;
        out_alpha[b * KMAX + t] = alpha;
        int cl2 = topc[b * MTOP + (j >> 7)];
        out_idx[b * KMAX + t] = (float)(cl2 * NPC + (j & 127));
    }
}

// ---------------- soft_full normalize ----------------
__global__ void k_norm(float* __restrict__ out_soft, const float* __restrict__ sums) {
    const int b = blockIdx.x >> 7;
    const int p = (blockIdx.x & 127) * 256 + threadIdx.x;
    const float inv = 1.0f / sums[b];
    float4* p4 = (float4*)(out_soft + (size_t)b * N_N) + p;
    float4 v = *p4;
    v.x *= inv; v.y *= inv; v.z *= inv; v.w *= inv;
    *p4 = v;
}

extern "C" void kernel_launch(void* const* d_in, const int* in_sizes, int n_in,
                              void* d_out, int out_size, void* d_ws, size_t ws_size,
                              hipStream_t stream) {
    const float* z    = (const float*)d_in[0];
    const float* keys = (const float*)d_in[1];
    const float* wqm  = (const float*)d_in[2];
    const float* aw   = (const float*)d_in[3];
    const float* tau  = (const float*)d_in[4];
    const float* cent = (const float*)d_in[5];
    const float* lam  = (const float*)d_in[6];
    const int*   warm = (const int*)d_in[7];
    float* out = (float*)d_out;
    float* out_alpha = out;                    // [64,64]
    float* out_idx   = out + B_N * KMAX;       // [64,64] (written as float values)
    float* out_soft  = out + 2 * B_N * KMAX;   // [64,131072]
    char* ws = (char*)d_ws;
    float*  qw   = (float*)(ws + 0);           // 131072 B
    float*  cn   = (float*)(ws + 131072);      // 2 MB
    double* cs   = (double*)(ws + 2228224);    // 512 KB
    int*    topc = (int*)(ws + 2752512);       // 8 KB
    int*    invm = (int*)(ws + 2760704);       // 256 KB
    double* si   = (double*)(ws + 3022848);    // 2 MB
    float*  sums = (float*)(ws + 5120000);     // 256 B

    hipLaunchKernelGGL(k_init,    dim3(1),    dim3(64),  0, stream, sums);
    hipLaunchKernelGGL(k_queries, dim3(256),  dim3(256), 0, stream, z, wqm, aw, qw);
    hipLaunchKernelGGL(k_cnorm,   dim3(1024), dim3(256), 0, stream, cent, cn);
    hipLaunchKernelGGL(k_cscore,  dim3(1024), dim3(256), 0, stream, qw, cn, cs);
    hipLaunchKernelGGL(k_top32,   dim3(64),   dim3(256), 0, stream, cs, topc, invm);
    hipLaunchKernelGGL(k_dense,   dim3(1024), dim3(256), 0, stream, keys, qw, invm, si, out_soft, sums);
    hipLaunchKernelGGL(k_top64,   dim3(64),   dim3(256), 0, stream, si, topc, tau, lam, warm, out_alpha, out_idx);
    hipLaunchKernelGGL(k_norm,    dim3(8192), dim3(256), 0, stream, out_soft, sums);
}